// Round 3
// baseline (303.941 us; speedup 1.0000x reference)
//
#include <hip/hip_runtime.h>
#include <hip/hip_bf16.h>
#include <math.h>

#define HIDDEN 512
#define ATTEN  512
#define BATCH  32
#define STEP   2048

#define BM 64                 // rows (positions) per scores block
#define BK 128                // K tile
#define THREADS 512           // 8 waves: 2 (M) x 4 (N)

#define NCH 16                // s-chunks in weighted-sum kernel
#define CHS (STEP / NCH)      // 128 positions per chunk

typedef __attribute__((ext_vector_type(8))) short bf16x8;
typedef __attribute__((ext_vector_type(4))) float f32x4;

// batch_lens may arrive as int64 (reference dtype) or int32 (jax without x64).
// Values are always >= 1, so for little-endian int64 the high word of elem 0
// (int32 view index 1) is 0; for int32 it's batch_lens[1] >= 1.
__device__ __forceinline__ long long load_len(const int* lens_raw, int b) {
    bool is64 = (lens_raw[1] == 0);
    if (is64) return ((const long long*)lens_raw)[b];
    return (long long)lens_raw[b];
}

__device__ __forceinline__ short f2bf(float x) {        // RNE fp32 -> bf16 bits
    unsigned u = __float_as_uint(x);
    unsigned r = (u + 0x7FFFu + ((u >> 16) & 1u)) >> 16;
    return (short)r;
}
__device__ __forceinline__ float bf2f(short s) {
    return __uint_as_float(((unsigned)(unsigned short)s) << 16);
}

__device__ __forceinline__ float fast_tanh(float x) {
    // tanh(x) = 1 - 2/(exp(2x)+1); exact saturation at +-inf, branchless
    float e = __expf(2.0f * x);
    return 1.0f - 2.0f / (e + 1.0f);
}

// K0: interleaved split-bf16 transpose of W.
// wtp layout (shorts): [(a*64 + kc)*16 + p*8 + j], kc=k-chunk of 8 (0..63),
// p=0:hi p=1:lo, j=0..7. So hi and lo 16B fragments share a 32B block ->
// one 64B line serves two k-chunks of both hi and lo. 1 MB, L2-resident.
__global__ __launch_bounds__(512) void wsplit_kernel(
    const float* __restrict__ W, short* __restrict__ wtp)
{
    int a = blockIdx.x;       // 0..511
    int h = threadIdx.x;      // 0..511
    float v = W[(size_t)h * ATTEN + a];
    short hi = f2bf(v);
    short lo = f2bf(v - bf2f(hi));
    size_t base = ((size_t)a * 64 + (h >> 3)) * 16 + (h & 7);
    wtp[base] = hi;
    wtp[base + 8] = lo;
}

// K1: scores[b,s] = sum_a tanh( X[b,s,:]·W[:,a] + bias[a] ) * ctx[a]
// Split-bf16 MFMA GEMM: block = 64 rows x all 512 atten cols, fused epilogue.
// 8 waves = 2(M) x 4(N); per wave mi=2 (32 rows) x ni=8 (128 cols).
__global__ __launch_bounds__(THREADS, 4) void scores_mfma_kernel(
    const float* __restrict__ X,        // [B*S*H] fp32
    const int*   __restrict__ lens_raw,
    const short* __restrict__ wtp,      // interleaved split-bf16 W^T
    const float* __restrict__ bias,     // [A]
    const float* __restrict__ ctx,      // [A]
    float* __restrict__ scores)         // [B*S]
{
    __shared__ char lds_raw[2 * BM * BK * 2];   // 32 KB: A-tile hi | lo

    const int tiles_per_b = STEP / BM;  // 32
    int b  = blockIdx.x / tiles_per_b;
    int s0 = (blockIdx.x % tiles_per_b) * BM;
    long long len = load_len(lens_raw, b);
    if ((long long)s0 >= len) return;   // softmax weight 0 for whole tile

    int t = threadIdx.x;
    int wave = t >> 6, lane = t & 63;
    int wrow = wave >> 2, wcol = wave & 3;      // 2 x 4 wave grid
    int l15 = lane & 15, l4 = lane >> 4;

    char* lds_hi = lds_raw;
    char* lds_lo = lds_raw + BM * BK * 2;

    f32x4 acc[2][8];                    // wave tile 32 x 128
#pragma unroll
    for (int mi = 0; mi < 2; ++mi)
#pragma unroll
        for (int ni = 0; ni < 8; ++ni)
            acc[mi][ni] = (f32x4){0.f, 0.f, 0.f, 0.f};

    const int colbase = wcol * 128 + l15;   // this lane's atten column (mod 16)

    // T14 async-STAGE: registers holding the next X sub-tile (2 chunks of 8)
    float4 pf[2][2];
    const int c0r = t >> 4, c0s = t & 15;           // chunk 0: row/slot
    const int c1r = (t + THREADS) >> 4, c1s = t & 15;  // chunk 1 (+512 -> row+32)
    const float* xbase = X + ((size_t)b * STEP + s0) * HIDDEN;

#define LOADX(KT)                                                          \
    do {                                                                   \
        const float* s_ = xbase + (size_t)c0r * HIDDEN + (KT) * BK + c0s * 8; \
        pf[0][0] = *(const float4*)(s_);                                   \
        pf[0][1] = *(const float4*)(s_ + 4);                               \
        const float* s2_ = xbase + (size_t)c1r * HIDDEN + (KT) * BK + c1s * 8; \
        pf[1][0] = *(const float4*)(s2_);                                  \
        pf[1][1] = *(const float4*)(s2_ + 4);                              \
    } while (0)

    LOADX(0);

    for (int kt = 0; kt < HIDDEN / BK; ++kt) {      // 4 K-tiles
        if (kt) __syncthreads();        // all waves done reading previous tile
        // convert prefetched fp32 -> hi/lo bf16, XOR-swizzled LDS write
#pragma unroll
        for (int it = 0; it < 2; ++it) {
            int row  = it ? c1r : c0r;
            int slot = it ? c1s : c0s;
            float xs[8] = {pf[it][0].x, pf[it][0].y, pf[it][0].z, pf[it][0].w,
                           pf[it][1].x, pf[it][1].y, pf[it][1].z, pf[it][1].w};
            bf16x8 hv, lv;
#pragma unroll
            for (int j = 0; j < 8; ++j) {
                short h = f2bf(xs[j]);
                hv[j] = h;
                lv[j] = f2bf(xs[j] - bf2f(h));
            }
            int off = row * (BK * 2) + ((slot * 16) ^ ((row & 7) << 4));
            *(bf16x8*)(lds_hi + off) = hv;
            *(bf16x8*)(lds_lo + off) = lv;
        }
        __syncthreads();
        if (kt < 3) LOADX(kt + 1);      // overlap next HBM fetch with MFMAs

#pragma unroll
        for (int kk = 0; kk < BK / 32; ++kk) {      // 4 K-steps
            bf16x8 ah[2], al[2];
#pragma unroll
            for (int mi = 0; mi < 2; ++mi) {
                int row = wrow * 32 + mi * 16 + l15;
                int kb  = kk * 64 + l4 * 16;        // byte col = 2*k
                int off = row * (BK * 2) + (kb ^ ((row & 7) << 4));
                ah[mi] = *(const bf16x8*)(lds_hi + off);
                al[mi] = *(const bf16x8*)(lds_lo + off);
            }
            int kc = kt * 16 + kk * 4 + l4;         // k-chunk of 8
#pragma unroll
            for (int ni = 0; ni < 8; ++ni) {
                const short* wp = wtp + ((size_t)(colbase + ni * 16) * 64 + kc) * 16;
                bf16x8 bh = *(const bf16x8*)(wp);
                bf16x8 bl = *(const bf16x8*)(wp + 8);
#pragma unroll
                for (int mi = 0; mi < 2; ++mi) {
                    acc[mi][ni] = __builtin_amdgcn_mfma_f32_16x16x32_bf16(
                        ah[mi], bh, acc[mi][ni], 0, 0, 0);
                    acc[mi][ni] = __builtin_amdgcn_mfma_f32_16x16x32_bf16(
                        ah[mi], bl, acc[mi][ni], 0, 0, 0);
                    acc[mi][ni] = __builtin_amdgcn_mfma_f32_16x16x32_bf16(
                        al[mi], bh, acc[mi][ni], 0, 0, 0);
                }
            }
        }
    }
#undef LOADX

    // fused epilogue: tanh(acc+bias)*ctx, reduce over all 512 cols
    float bi[8], ci[8];
#pragma unroll
    for (int ni = 0; ni < 8; ++ni) {
        int a = colbase + ni * 16;
        bi[ni] = bias[a];
        ci[ni] = ctx[a];
    }
    __syncthreads();                        // done reading A-tile LDS
    float* partial = (float*)lds_raw;       // [4 wcol][BM]
#pragma unroll
    for (int mi = 0; mi < 2; ++mi) {
#pragma unroll
        for (int reg = 0; reg < 4; ++reg) {
            float s = 0.f;
#pragma unroll
            for (int ni = 0; ni < 8; ++ni)
                s += fast_tanh(acc[mi][ni][reg] + bi[ni]) * ci[ni];
            // reduce over the 16 lanes sharing this output row
            s += __shfl_xor(s, 1);
            s += __shfl_xor(s, 2);
            s += __shfl_xor(s, 4);
            s += __shfl_xor(s, 8);
            if (l15 == 0) {
                int row = wrow * 32 + mi * 16 + l4 * 4 + reg;  // C/D: row=(l>>4)*4+reg
                partial[wcol * BM + row] = s;
            }
        }
    }
    __syncthreads();
    if (t < BM) {
        float v = partial[0 * BM + t] + partial[1 * BM + t]
                + partial[2 * BM + t] + partial[3 * BM + t];
        scores[(size_t)b * STEP + s0 + t] = v;
    }
}

// K2: masked softmax per batch row (deterministic tree reductions)
__global__ __launch_bounds__(256) void softmax_kernel(
    const float* __restrict__ scores, const int* __restrict__ lens_raw,
    float* __restrict__ atten)
{
    __shared__ float wmax[4], wsum[4];
    int b = blockIdx.x;
    long long len = load_len(lens_raw, b);
    int t = threadIdx.x;
    const float* srow = scores + (size_t)b * STEP;
    float* arow = atten + (size_t)b * STEP;

    float sv[STEP / 256];
    float locmax = -INFINITY;
#pragma unroll
    for (int k = 0; k < 8; ++k) {
        int s = t + k * 256;
        float v = ((long long)s < len) ? srow[s] : -INFINITY;
        sv[k] = v;
        locmax = fmaxf(locmax, v);
    }
    for (int o = 1; o < 64; o <<= 1) locmax = fmaxf(locmax, __shfl_xor(locmax, o));
    int wave = t >> 6, lane = t & 63;
    if (lane == 0) wmax[wave] = locmax;
    __syncthreads();
    float gmax = fmaxf(fmaxf(wmax[0], wmax[1]), fmaxf(wmax[2], wmax[3]));

    float ev[8];
    float locsum = 0.f;
#pragma unroll
    for (int k = 0; k < 8; ++k) {
        float e = (sv[k] == -INFINITY) ? 0.f : expf(sv[k] - gmax);
        ev[k] = e;
        locsum += e;
    }
    for (int o = 1; o < 64; o <<= 1) locsum += __shfl_xor(locsum, o);
    if (lane == 0) wsum[wave] = locsum;
    __syncthreads();
    float inv = 1.f / (wsum[0] + wsum[1] + wsum[2] + wsum[3]);
#pragma unroll
    for (int k = 0; k < 8; ++k) {
        int s = t + k * 256;
        arow[s] = ev[k] * inv;    // padded positions get exact 0
    }
}

// K3a: partial[b,ch,h] = sum_{s in chunk, s<len} atten[b,s] * X[b,s,h]
__global__ __launch_bounds__(256) void wsum_kernel(
    const float* __restrict__ X, const int* __restrict__ lens_raw,
    const float* __restrict__ atten, float* __restrict__ partial)
{
    int ch = blockIdx.x;
    int b  = blockIdx.y;
    long long len = load_len(lens_raw, b);
    int t = threadIdx.x;
    int s0 = ch * CHS;
    long long send_ll = (long long)(s0 + CHS);
    if (send_ll > len) send_ll = len;
    int send = (int)send_ll;

    const float* arow = atten + (size_t)b * STEP;
    float acc0 = 0.f, acc1 = 0.f;
    for (int s = s0; s < send; ++s) {
        float a = arow[s];
        const float* xr = X + ((size_t)b * STEP + s) * HIDDEN;
        acc0 = fmaf(a, xr[t], acc0);
        acc1 = fmaf(a, xr[t + 256], acc1);
    }
    float* prow = partial + ((size_t)b * NCH + ch) * HIDDEN;
    prow[t] = acc0;            // skipped chunks write zeros
    prow[t + 256] = acc1;
}

// K3b: out[b,h] = sum_ch partial[b,ch,h]
__global__ __launch_bounds__(256) void finalize_kernel(
    const float* __restrict__ partial, float* __restrict__ out)
{
    int b = blockIdx.x;
    int t = threadIdx.x;
    float a0 = 0.f, a1 = 0.f;
#pragma unroll
    for (int ch = 0; ch < NCH; ++ch) {
        const float* prow = partial + ((size_t)b * NCH + ch) * HIDDEN;
        a0 += prow[t];
        a1 += prow[t + 256];
    }
    out[(size_t)b * HIDDEN + t] = a0;
    out[(size_t)b * HIDDEN + t + 256] = a1;
}

extern "C" void kernel_launch(void* const* d_in, const int* in_sizes, int n_in,
                              void* d_out, int out_size, void* d_ws, size_t ws_size,
                              hipStream_t stream) {
    const float* X    = (const float*)d_in[0];
    const int*   lens = (const int*)d_in[1];   // dtype sniffed on device
    const float* W    = (const float*)d_in[2];
    const float* bias = (const float*)d_in[3];
    const float* ctx  = (const float*)d_in[4];
    float* out = (float*)d_out;

    char* ws = (char*)d_ws;
    float* scores  = (float*)ws;                              // 256 KB
    float* atten   = (float*)(ws + 256 * 1024);               // 256 KB
    float* partial = (float*)(ws + 512 * 1024);               // 1 MB
    short* wtp     = (short*)(ws + 512 * 1024 + 1024 * 1024); // 1 MB interleaved

    wsplit_kernel<<<dim3(ATTEN), 512, 0, stream>>>(W, wtp);
    scores_mfma_kernel<<<dim3(BATCH * (STEP / BM)), THREADS, 0, stream>>>(
        X, lens, wtp, bias, ctx, scores);
    softmax_kernel<<<dim3(BATCH), 256, 0, stream>>>(scores, lens, atten);
    wsum_kernel<<<dim3(NCH, BATCH), 256, 0, stream>>>(X, lens, atten, partial);
    finalize_kernel<<<dim3(BATCH), 256, 0, stream>>>(partial, out);
}

// Round 4
// 135.613 us; speedup vs baseline: 2.2412x; 2.2412x over previous
//
#include <hip/hip_runtime.h>
#include <hip/hip_bf16.h>
#include <math.h>

#define HIDDEN 512
#define ATTEN  512
#define BATCH  32
#define STEP   2048

#define BM 128                // rows per scores block
#define BN 256                // atten cols per block (2 N-slices)
#define BK 32                 // K tile
#define NT (HIDDEN / BK)      // 16 K-tiles
#define THREADS 512           // 8 waves: 2(M) x 4(N), wave tile 64x64

#define NCH 16                // s-chunks in weighted-sum kernel
#define CHS (STEP / NCH)

typedef __attribute__((ext_vector_type(8))) short bf16x8;
typedef __attribute__((ext_vector_type(4))) float f32x4;

// batch_lens may arrive as int64 (reference dtype) or int32 (jax without x64).
// Values >= 1, so int32-view index 1 == 0 iff the buffer is int64.
__device__ __forceinline__ long long load_len(const int* lens_raw, int b) {
    bool is64 = (lens_raw[1] == 0);
    if (is64) return ((const long long*)lens_raw)[b];
    return (long long)lens_raw[b];
}

__device__ __forceinline__ short f2bf(float x) {        // RNE fp32 -> bf16 bits
    unsigned u = __float_as_uint(x);
    unsigned r = (u + 0x7FFFu + ((u >> 16) & 1u)) >> 16;
    return (short)r;
}
__device__ __forceinline__ float bf2f(short s) {
    return __uint_as_float(((unsigned)(unsigned short)s) << 16);
}

__device__ __forceinline__ float fast_tanh(float x) {
    float e = __expf(2.0f * x);         // saturates correctly at +-inf
    return 1.0f - 2.0f / (e + 1.0f);
}

// K0: pre-swizzled split-bf16 W for global_load_lds staging.
// LDS B layout (per N-slice ns, K-tile kt): col c(0..255) row of 128B =
// 8 slots of 16B; slot16 = (p*4 + s) ^ (c&7), p=hi/lo, s=k-subslot(8 bf16).
// global_load_lds writes chunk n -> LDS byte n*16, so global chunk order is
// n = c*8 + slot16. wglds[((ns*16+kt)*2048 + n)*8 + j].
__global__ __launch_bounds__(512) void wsplit_kernel(
    const float* __restrict__ W, short* __restrict__ wglds)
{
    int a = blockIdx.x;       // 0..511  (atten col)
    int h = threadIdx.x;      // 0..511  (hidden = k)
    float v = W[(size_t)h * ATTEN + a];
    short hi = f2bf(v);
    short lo = f2bf(v - bf2f(hi));
    int ns = a >> 8, c = a & 255;
    int kt = h >> 5, s = (h >> 3) & 3, j = h & 7;
    size_t tb = ((size_t)ns * NT + kt) * 2048;
    int n_hi = c * 8 + ((s) ^ (c & 7));
    int n_lo = c * 8 + ((4 + s) ^ (c & 7));
    wglds[(tb + n_hi) * 8 + j] = hi;
    wglds[(tb + n_lo) * 8 + j] = lo;
}

// K1: partial scores over a 256-col slice; both operands LDS-staged.
__global__ __launch_bounds__(THREADS, 4) void scores_mfma_kernel(
    const float* __restrict__ X,        // [B*S*H] fp32
    const int*   __restrict__ lens_raw,
    const short* __restrict__ wglds,    // pre-swizzled split-bf16 W
    const float* __restrict__ bias,
    const float* __restrict__ ctx,
    float* __restrict__ scores_part)    // [2][B*S]
{
    __shared__ char smem[48 * 1024];
    char* smA = smem;                   // 16 KB: A hi/lo, swizzled
    char* smB = smem + 16 * 1024;       // 32 KB: B hi/lo, swizzled

    const int tiles_per_b = STEP / BM;  // 16
    int mt = blockIdx.x;
    int ns = blockIdx.y;                // N-slice 0/1
    int b  = mt / tiles_per_b;
    int s0 = (mt % tiles_per_b) * BM;
    long long len = load_len(lens_raw, b);
    if ((long long)s0 >= len) return;

    int t = threadIdx.x;
    int wave = t >> 6, lane = t & 63;
    int wrow = wave >> 2, wcol = wave & 3;
    int l15 = lane & 15, l4 = lane >> 4;

    // A staging coords: thread -> (row ar, k-subslot aq)
    int ar = t >> 2, aq = t & 3;
    const float* xrow = X + ((size_t)b * STEP + s0 + ar) * HIDDEN + aq * 8;

    const short* wbase = wglds + ((size_t)ns * NT) * 2048 * 8;
    int wvuni = t & ~63;                // wave-uniform lds base component

    f32x4 acc[4][4];
#pragma unroll
    for (int mi = 0; mi < 4; ++mi)
#pragma unroll
        for (int ni = 0; ni < 4; ++ni)
            acc[mi][ni] = (f32x4){0.f, 0.f, 0.f, 0.f};

#define STAGE(KT)                                                            \
    do {                                                                     \
        _Pragma("unroll")                                                    \
        for (int i = 0; i < 4; ++i) {  /* B: 32 KB via global_load_lds */    \
            const short* g = wbase + ((size_t)(KT) * 2048 + i * 512 + t) * 8;\
            char* l = smB + (i * 512 + wvuni) * 16;                          \
            __builtin_amdgcn_global_load_lds(                                \
                (const __attribute__((address_space(1))) unsigned int*)g,    \
                (__attribute__((address_space(3))) unsigned int*)l,          \
                16, 0, 0);                                                   \
        }                                                                    \
        float4 x0 = *(const float4*)(xrow + (KT) * BK);                      \
        float4 x1 = *(const float4*)(xrow + (KT) * BK + 4);                  \
        float xs[8] = {x0.x, x0.y, x0.z, x0.w, x1.x, x1.y, x1.z, x1.w};      \
        bf16x8 hv, lv;                                                       \
        _Pragma("unroll")                                                    \
        for (int j = 0; j < 8; ++j) {                                        \
            short h_ = f2bf(xs[j]);                                          \
            hv[j] = h_;                                                      \
            lv[j] = f2bf(xs[j] - bf2f(h_));                                  \
        }                                                                    \
        int rx = ar & 7;                                                     \
        *(bf16x8*)(smA + ar * 128 + (((aq) ^ rx) << 4)) = hv;                \
        *(bf16x8*)(smA + ar * 128 + (((4 + aq) ^ rx) << 4)) = lv;            \
    } while (0)

    STAGE(0);
    __syncthreads();

    for (int kt = 0; kt < NT; ++kt) {
        // compute current tile: 1 K-step of 32, 48 MFMAs/wave
        bf16x8 ah[4], al[4];
#pragma unroll
        for (int mi = 0; mi < 4; ++mi) {
            int row = wrow * 64 + mi * 16 + l15;
            int rx = row & 7;
            ah[mi] = *(const bf16x8*)(smA + row * 128 + ((l4 ^ rx) << 4));
            al[mi] = *(const bf16x8*)(smA + row * 128 + (((4 + l4) ^ rx) << 4));
        }
#pragma unroll
        for (int ni = 0; ni < 4; ++ni) {
            int col = wcol * 64 + ni * 16 + l15;
            int cx = col & 7;
            bf16x8 bh = *(const bf16x8*)(smB + col * 128 + ((l4 ^ cx) << 4));
            bf16x8 bl = *(const bf16x8*)(smB + col * 128 + (((4 + l4) ^ cx) << 4));
#pragma unroll
            for (int mi = 0; mi < 4; ++mi) {
                acc[mi][ni] = __builtin_amdgcn_mfma_f32_16x16x32_bf16(
                    ah[mi], bh, acc[mi][ni], 0, 0, 0);
                acc[mi][ni] = __builtin_amdgcn_mfma_f32_16x16x32_bf16(
                    ah[mi], bl, acc[mi][ni], 0, 0, 0);
                acc[mi][ni] = __builtin_amdgcn_mfma_f32_16x16x32_bf16(
                    al[mi], bh, acc[mi][ni], 0, 0, 0);
            }
        }
        __syncthreads();                 // all reads of smem done
        if (kt + 1 < NT) {
            STAGE(kt + 1);
            __syncthreads();             // drains DMA (vmcnt) + ds_writes
        }
    }
#undef STAGE

    // fused epilogue: tanh(acc+bias)*ctx reduced over this slice's 256 cols
    float bi[4], ci[4];
#pragma unroll
    for (int ni = 0; ni < 4; ++ni) {
        int a = ns * BN + wcol * 64 + ni * 16 + l15;
        bi[ni] = bias[a];
        ci[ni] = ctx[a];
    }
    float* partial = (float*)smA;        // [4 wcol][BM]
#pragma unroll
    for (int mi = 0; mi < 4; ++mi) {
#pragma unroll
        for (int reg = 0; reg < 4; ++reg) {
            float s = 0.f;
#pragma unroll
            for (int ni = 0; ni < 4; ++ni)
                s += fast_tanh(acc[mi][ni][reg] + bi[ni]) * ci[ni];
            s += __shfl_xor(s, 1);
            s += __shfl_xor(s, 2);
            s += __shfl_xor(s, 4);
            s += __shfl_xor(s, 8);
            if (l15 == 0) {
                int row = wrow * 64 + mi * 16 + l4 * 4 + reg;  // C/D layout
                partial[wcol * BM + row] = s;
            }
        }
    }
    __syncthreads();
    if (t < BM) {
        float v = partial[0 * BM + t] + partial[1 * BM + t]
                + partial[2 * BM + t] + partial[3 * BM + t];
        scores_part[((size_t)ns * BATCH + b) * STEP + s0 + t] = v;
    }
}

// K2: masked softmax; sums the 2 N-slice partials; atten aliases slice-0
// buffer (each thread reads its s-values before writing them).
__global__ __launch_bounds__(256) void softmax_kernel(
    const float* __restrict__ p0, const float* __restrict__ p1,
    const int* __restrict__ lens_raw, float* __restrict__ atten)
{
    __shared__ float wmax[4], wsum[4];
    int b = blockIdx.x;
    long long len = load_len(lens_raw, b);
    int t = threadIdx.x;
    const float* r0 = p0 + (size_t)b * STEP;
    const float* r1 = p1 + (size_t)b * STEP;
    float* arow = atten + (size_t)b * STEP;

    float sv[STEP / 256];
    float locmax = -INFINITY;
#pragma unroll
    for (int k = 0; k < 8; ++k) {
        int s = t + k * 256;
        float v = ((long long)s < len) ? (r0[s] + r1[s]) : -INFINITY;
        sv[k] = v;
        locmax = fmaxf(locmax, v);
    }
    for (int o = 1; o < 64; o <<= 1) locmax = fmaxf(locmax, __shfl_xor(locmax, o));
    int wave = t >> 6, lane = t & 63;
    if (lane == 0) wmax[wave] = locmax;
    __syncthreads();
    float gmax = fmaxf(fmaxf(wmax[0], wmax[1]), fmaxf(wmax[2], wmax[3]));

    float ev[8];
    float locsum = 0.f;
#pragma unroll
    for (int k = 0; k < 8; ++k) {
        float e = (sv[k] == -INFINITY) ? 0.f : expf(sv[k] - gmax);
        ev[k] = e;
        locsum += e;
    }
    for (int o = 1; o < 64; o <<= 1) locsum += __shfl_xor(locsum, o);
    if (lane == 0) wsum[wave] = locsum;
    __syncthreads();
    float inv = 1.f / (wsum[0] + wsum[1] + wsum[2] + wsum[3]);
#pragma unroll
    for (int k = 0; k < 8; ++k) {
        int s = t + k * 256;
        arow[s] = ev[k] * inv;
    }
}

// K3a: partial[b,ch,h] = sum_{s in chunk, s<len} atten[b,s] * X[b,s,h]
__global__ __launch_bounds__(256) void wsum_kernel(
    const float* __restrict__ X, const int* __restrict__ lens_raw,
    const float* __restrict__ atten, float* __restrict__ partial)
{
    int ch = blockIdx.x;
    int b  = blockIdx.y;
    long long len = load_len(lens_raw, b);
    int t = threadIdx.x;
    int s0 = ch * CHS;
    long long send_ll = (long long)(s0 + CHS);
    if (send_ll > len) send_ll = len;
    int send = (int)send_ll;

    const float* arow = atten + (size_t)b * STEP;
    float acc0 = 0.f, acc1 = 0.f;
    for (int s = s0; s < send; ++s) {
        float a = arow[s];
        const float* xr = X + ((size_t)b * STEP + s) * HIDDEN;
        acc0 = fmaf(a, xr[t], acc0);
        acc1 = fmaf(a, xr[t + 256], acc1);
    }
    float* prow = partial + ((size_t)b * NCH + ch) * HIDDEN;
    prow[t] = acc0;            // skipped chunks write zeros
    prow[t + 256] = acc1;
}

// K3b: out[b,h] = sum_ch partial[b,ch,h]
__global__ __launch_bounds__(256) void finalize_kernel(
    const float* __restrict__ partial, float* __restrict__ out)
{
    int b = blockIdx.x;
    int t = threadIdx.x;
    float a0 = 0.f, a1 = 0.f;
#pragma unroll
    for (int ch = 0; ch < NCH; ++ch) {
        const float* prow = partial + ((size_t)b * NCH + ch) * HIDDEN;
        a0 += prow[t];
        a1 += prow[t + 256];
    }
    out[(size_t)b * HIDDEN + t] = a0;
    out[(size_t)b * HIDDEN + t + 256] = a1;
}

extern "C" void kernel_launch(void* const* d_in, const int* in_sizes, int n_in,
                              void* d_out, int out_size, void* d_ws, size_t ws_size,
                              hipStream_t stream) {
    const float* X    = (const float*)d_in[0];
    const int*   lens = (const int*)d_in[1];   // dtype sniffed on device
    const float* W    = (const float*)d_in[2];
    const float* bias = (const float*)d_in[3];
    const float* ctx  = (const float*)d_in[4];
    float* out = (float*)d_out;

    char* ws = (char*)d_ws;
    float* sp      = (float*)ws;                   // [2][B*S] = 512 KB
    float* atten   = sp;                           // aliases slice-0 (safe)
    float* partial = (float*)(ws + 512 * 1024);    // 1 MB
    short* wglds   = (short*)(ws + 1536 * 1024);   // 1 MB pre-swizzled W

    wsplit_kernel<<<dim3(ATTEN), 512, 0, stream>>>(W, wglds);
    scores_mfma_kernel<<<dim3(BATCH * (STEP / BM), ATTEN / BN), THREADS, 0, stream>>>(
        X, lens, wglds, bias, ctx, sp);
    softmax_kernel<<<dim3(BATCH), 256, 0, stream>>>(
        sp, sp + (size_t)BATCH * STEP, lens, atten);
    wsum_kernel<<<dim3(NCH, BATCH), 256, 0, stream>>>(X, lens, atten, partial);
    finalize_kernel<<<dim3(BATCH), 256, 0, stream>>>(partial, out);
}